// Round 1
// baseline (671.918 us; speedup 1.0000x reference)
//
#include <hip/hip_runtime.h>
#include <math.h>

// ---------------------------------------------------------------------------
// HDRNet (bilateral guided upsampling) pipeline, N=4, low 256x256, full 1024x1024
// Workspace float layout (all fp32):
//   t0    (4,8,128,128)   524288
//   t1    (4,16,64,64)    262144
//   t2    (4,32,32,32)    131072
//   splat (4,64,16,16)     65536
//   l0o   (4,64,16,16)     65536
//   local (4,64,16,16)     65536
//   x1    (4,128,8,8)      32768
//   x2    (4,256,4,4)      16384
//   avec  (4,448)           1792
//   glob  (4,64)             256
//   grid  (4,96,16,16)     98304   == (4,12,8,16,16)
// ---------------------------------------------------------------------------

__device__ __forceinline__ float tanh_fast(float x) {
    // tanh(x) = 1 - 2/(exp(2x)+1); robust at +/-inf
    float e = __expf(2.0f * x);
    return 1.0f - 2.0f / (e + 1.0f);
}

// Generic 3x3 stride-2 pad-1 conv + bias + relu, one thread per output elem.
__global__ __launch_bounds__(256) void conv3x3_s2_relu(
    const float* __restrict__ in, const float* __restrict__ w,
    const float* __restrict__ b, float* __restrict__ out,
    int N, int Cin, int Hin, int Win, int Cout, int Hout, int Wout)
{
    int idx = blockIdx.x * blockDim.x + threadIdx.x;
    int total = N * Cout * Hout * Wout;
    if (idx >= total) return;
    int wo = idx % Wout; int t = idx / Wout;
    int ho = t % Hout; t /= Hout;
    int co = t % Cout; int n = t / Cout;
    float acc = b[co];
    int hi0 = ho * 2 - 1, wi0 = wo * 2 - 1;
    const float* wp = w + co * Cin * 9;
    for (int ci = 0; ci < Cin; ++ci) {
        const float* ip = in + ((size_t)(n * Cin + ci)) * Hin * Win;
        const float* wc = wp + ci * 9;
        #pragma unroll
        for (int kh = 0; kh < 3; ++kh) {
            int hi = hi0 + kh;
            if (hi < 0 || hi >= Hin) continue;
            const float* row = ip + hi * Win;
            #pragma unroll
            for (int kw = 0; kw < 3; ++kw) {
                int wi = wi0 + kw;
                if (wi < 0 || wi >= Win) continue;
                acc = fmaf(wc[kh * 3 + kw], row[wi], acc);
            }
        }
    }
    out[idx] = fmaxf(acc, 0.0f);
}

// 3x3 stride-1 pad-1 conv on (4,64,16,16); bias optional, relu optional
__global__ __launch_bounds__(256) void conv3x3_s1_64(
    const float* __restrict__ in, const float* __restrict__ w,
    const float* __restrict__ b, float* __restrict__ out, int do_relu)
{
    int idx = blockIdx.x * blockDim.x + threadIdx.x;   // 4*64*256 = 65536
    if (idx >= 4 * 64 * 256) return;
    int x = idx & 15; int y = (idx >> 4) & 15;
    int co = (idx >> 8) & 63; int n = idx >> 14;
    float acc = b ? b[co] : 0.0f;
    const float* wp = w + co * 64 * 9;
    const float* ip = in + n * 64 * 256;
    for (int ci = 0; ci < 64; ++ci) {
        const float* ic = ip + ci * 256;
        const float* wc = wp + ci * 9;
        #pragma unroll
        for (int kh = 0; kh < 3; ++kh) {
            int yy = y + kh - 1;
            if (yy < 0 || yy > 15) continue;
            #pragma unroll
            for (int kw = 0; kw < 3; ++kw) {
                int xx = x + kw - 1;
                if (xx < 0 || xx > 15) continue;
                acc = fmaf(wc[kh * 3 + kw], ic[yy * 16 + xx], acc);
            }
        }
    }
    if (do_relu) acc = fmaxf(acc, 0.0f);
    out[idx] = acc;
}

// avec[n][0:64]=mean(splat), [64:192]=mean(x1), [192:448]=mean(x2)
__global__ __launch_bounds__(256) void means_kernel(
    const float* __restrict__ splat, const float* __restrict__ x1,
    const float* __restrict__ x2, float* __restrict__ avec)
{
    int idx = blockIdx.x * blockDim.x + threadIdx.x;   // 4*448 = 1792
    if (idx >= 4 * 448) return;
    int n = idx / 448; int c = idx % 448;
    float s = 0.0f;
    if (c < 64) {
        const float* p = splat + (n * 64 + c) * 256;
        for (int i = 0; i < 256; ++i) s += p[i];
        s *= (1.0f / 256.0f);
    } else if (c < 192) {
        const float* p = x1 + (n * 128 + (c - 64)) * 64;
        for (int i = 0; i < 64; ++i) s += p[i];
        s *= (1.0f / 64.0f);
    } else {
        const float* p = x2 + (n * 256 + (c - 192)) * 16;
        for (int i = 0; i < 16; ++i) s += p[i];
        s *= (1.0f / 16.0f);
    }
    avec[idx] = s;
}

// Fused FC chain: 448 -> 256 -> 128 -> 64, all relu. One block per image.
__global__ __launch_bounds__(256) void fc_fused(
    const float* __restrict__ avec,
    const float* __restrict__ wf1, const float* __restrict__ bf1,
    const float* __restrict__ wf2, const float* __restrict__ bf2,
    const float* __restrict__ wf3, const float* __restrict__ bf3,
    float* __restrict__ glob)
{
    __shared__ float a[448];
    __shared__ float h1[256];
    __shared__ float h2[128];
    int n = blockIdx.x, t = threadIdx.x;
    for (int i = t; i < 448; i += 256) a[i] = avec[n * 448 + i];
    __syncthreads();
    {
        float acc = bf1[t];
        const float* wp = wf1 + t * 448;
        for (int i = 0; i < 448; ++i) acc = fmaf(wp[i], a[i], acc);
        h1[t] = fmaxf(acc, 0.0f);
    }
    __syncthreads();
    if (t < 128) {
        float acc = bf2[t];
        const float* wp = wf2 + t * 256;
        for (int i = 0; i < 256; ++i) acc = fmaf(wp[i], h1[i], acc);
        h2[t] = fmaxf(acc, 0.0f);
    }
    __syncthreads();
    if (t < 64) {
        float acc = bf3[t];
        const float* wp = wf3 + t * 128;
        for (int i = 0; i < 128; ++i) acc = fmaf(wp[i], h2[i], acc);
        glob[n * 64 + t] = fmaxf(acc, 0.0f);
    }
}

// grid[n][k][p] = blin[k] + sum_c wlin[k][c] * relu(glob[n][c] + local[n][c][p])
__global__ __launch_bounds__(256) void fuse_grid(
    const float* __restrict__ glob, const float* __restrict__ local,
    const float* __restrict__ wlin, const float* __restrict__ blin,
    float* __restrict__ grid)
{
    int idx = blockIdx.x * blockDim.x + threadIdx.x;   // 4*96*256 = 98304
    if (idx >= 4 * 96 * 256) return;
    int p = idx & 255; int k = (idx >> 8) % 96; int n = idx / (96 * 256);
    float acc = blin[k];
    const float* wp = wlin + k * 64;
    const float* gl = glob + n * 64;
    const float* lo = local + n * 64 * 256 + p;
    for (int c = 0; c < 64; ++c)
        acc = fmaf(wp[c], fmaxf(gl[c] + lo[c * 256], 0.0f), acc);
    grid[idx] = acc;
}

// The big fused full-res kernel: guide conv -> tanh -> trilinear slice ->
// YUV assembly -> U/V 1x1 towers -> + bilinear-upsampled fake chroma.
__global__ __launch_bounds__(256) void hdr_out_kernel(
    const float* __restrict__ full, const float* __restrict__ low,
    const float* __restrict__ grid,
    const float* __restrict__ wgd1, const float* __restrict__ bgd1,
    const float* __restrict__ wgd2, const float* __restrict__ bgd2,
    const float* __restrict__ wau1, const float* __restrict__ bau1,
    const float* __restrict__ wau2, const float* __restrict__ bau2,
    const float* __restrict__ wav1, const float* __restrict__ bav1,
    const float* __restrict__ wav2, const float* __restrict__ bav2,
    float* __restrict__ out)
{
    const int W = 1024, H = 1024;
    int idx = blockIdx.x * blockDim.x + threadIdx.x;   // 4*1024*1024
    int x = idx & (W - 1);
    int y = (idx >> 10) & (H - 1);
    int n = idx >> 20;
    const float* fp = full + (size_t)n * H * W;

    // 3x3 neighborhood, zero padded
    float v[3][3];
    #pragma unroll
    for (int dy = 0; dy < 3; ++dy) {
        int yy = y + dy - 1;
        #pragma unroll
        for (int dx = 0; dx < 3; ++dx) {
            int xx = x + dx - 1;
            v[dy][dx] = (yy >= 0 && yy < H && xx >= 0 && xx < W) ? fp[yy * W + xx] : 0.0f;
        }
    }

    // guide = tanh(1x1(relu(3x3 conv)))
    float gacc = bgd2[0];
    #pragma unroll
    for (int k = 0; k < 16; ++k) {
        float h = bgd1[k];
        const float* wk = wgd1 + k * 9;
        #pragma unroll
        for (int dy = 0; dy < 3; ++dy)
            #pragma unroll
            for (int dx = 0; dx < 3; ++dx)
                h = fmaf(wk[dy * 3 + dx], v[dy][dx], h);
        gacc = fmaf(wgd2[k], fmaxf(h, 0.0f), gacc);
    }
    float g = tanh_fast(gacc);

    // trilinear slice coords (align_corners=False grid_sample semantics)
    float gxc = (x * (32.0f / 1023.0f) - 1.0f) * 0.5f;
    float gyc = (y * (32.0f / 1023.0f) - 1.0f) * 0.5f;
    float gzc = 4.0f * g + 3.5f;
    float x0f = floorf(gxc), y0f = floorf(gyc), z0f = floorf(gzc);
    float fx = gxc - x0f, fy = gyc - y0f, fz = gzc - z0f;
    int x0 = (int)x0f, y0 = (int)y0f, z0 = (int)z0f;

    float wx0 = (x0 >= 0 && x0 < 16) ? (1.0f - fx) : 0.0f;
    float wx1 = (x0 + 1 >= 0 && x0 + 1 < 16) ? fx : 0.0f;
    float wy0 = (y0 >= 0 && y0 < 16) ? (1.0f - fy) : 0.0f;
    float wy1 = (y0 + 1 >= 0 && y0 + 1 < 16) ? fy : 0.0f;
    float wz0 = (z0 >= 0 && z0 < 8) ? (1.0f - fz) : 0.0f;
    float wz1 = (z0 + 1 >= 0 && z0 + 1 < 8) ? fz : 0.0f;
    int xi0 = min(max(x0, 0), 15), xi1 = min(max(x0 + 1, 0), 15);
    int yi0 = min(max(y0, 0), 15), yi1 = min(max(y0 + 1, 0), 15);
    int zi0 = min(max(z0, 0), 7),  zi1 = min(max(z0 + 1, 0), 7);

    float w00 = wy0 * wx0, w01 = wy0 * wx1, w10 = wy1 * wx0, w11 = wy1 * wx1;
    int o00 = yi0 * 16 + xi0, o01 = yi0 * 16 + xi1;
    int o10 = yi1 * 16 + xi0, o11 = yi1 * 16 + xi1;
    const float* gp = grid + n * 12 * 8 * 256;
    int zo0 = zi0 * 256, zo1 = zi1 * 256;

    float c[12];
    #pragma unroll
    for (int ch = 0; ch < 12; ++ch) {
        const float* gc = gp + ch * 2048;
        const float* g0 = gc + zo0;
        const float* g1 = gc + zo1;
        float b0 = w00 * g0[o00] + w01 * g0[o01] + w10 * g0[o10] + w11 * g0[o11];
        float b1 = w00 * g1[o00] + w01 * g1[o01] + w10 * g1[o10] + w11 * g1[o11];
        c[ch] = wz0 * b0 + wz1 * b1;
    }

    float p = v[1][1];
    float Yv = fmaf(p, c[3],  c[0] + c[1] + c[2]);
    float U0 = fmaf(p, c[7],  c[4] + c[5] + c[6]);
    float V0 = fmaf(p, c[11], c[8] + c[9] + c[10]);

    // U/V towers: 1 -> 16 relu -> 1, tanh; purely per-pixel
    float uacc = bau2[0];
    #pragma unroll
    for (int k = 0; k < 16; ++k)
        uacc = fmaf(wau2[k], fmaxf(fmaf(wau1[k], U0, bau1[k]), 0.0f), uacc);
    float vacc = bav2[0];
    #pragma unroll
    for (int k = 0; k < 16; ++k)
        vacc = fmaf(wav2[k], fmaxf(fmaf(wav1[k], V0, bav1[k]), 0.0f), vacc);

    // fake chroma: bilinear upsample 256->1024, half-pixel centers, edge clamp
    float sx = (x + 0.5f) * 0.25f - 0.5f;
    float sy = (y + 0.5f) * 0.25f - 0.5f;
    float sxf = floorf(sx), syf = floorf(sy);
    float fxl = sx - sxf, fyl = sy - syf;
    int ix0 = (int)sxf, iy0 = (int)syf;
    int ix0c = max(ix0, 0), ix1c = min(ix0 + 1, 255);
    int iy0c = max(iy0, 0), iy1c = min(iy0 + 1, 255);
    const float* lr1 = low + ((size_t)(n * 3 + 1)) * 65536;
    const float* lr2 = low + ((size_t)(n * 3 + 2)) * 65536;
    float f1 = (1.0f - fyl) * ((1.0f - fxl) * lr1[iy0c * 256 + ix0c] + fxl * lr1[iy0c * 256 + ix1c])
             + fyl * ((1.0f - fxl) * lr1[iy1c * 256 + ix0c] + fxl * lr1[iy1c * 256 + ix1c]);
    float f2 = (1.0f - fyl) * ((1.0f - fxl) * lr2[iy0c * 256 + ix0c] + fxl * lr2[iy0c * 256 + ix1c])
             + fyl * ((1.0f - fxl) * lr2[iy1c * 256 + ix0c] + fxl * lr2[iy1c * 256 + ix1c]);

    float Uv = tanh_fast(uacc) + f1;
    float Vv = tanh_fast(vacc) + f2;

    size_t base = (size_t)n * 3 * H * W + (size_t)y * W + x;
    out[base] = Yv;
    out[base + (size_t)H * W] = Uv;
    out[base + (size_t)2 * H * W] = Vv;
}

extern "C" void kernel_launch(void* const* d_in, const int* in_sizes, int n_in,
                              void* d_out, int out_size, void* d_ws, size_t ws_size,
                              hipStream_t stream)
{
    const float* low  = (const float*)d_in[0];
    const float* full = (const float*)d_in[1];
    const float* w0 = (const float*)d_in[2];  const float* b0 = (const float*)d_in[3];
    const float* w1 = (const float*)d_in[4];  const float* b1 = (const float*)d_in[5];
    const float* w2 = (const float*)d_in[6];  const float* b2 = (const float*)d_in[7];
    const float* w3 = (const float*)d_in[8];  const float* b3 = (const float*)d_in[9];
    const float* wl0 = (const float*)d_in[10]; const float* bl0 = (const float*)d_in[11];
    const float* wl1 = (const float*)d_in[12];
    const float* wg1 = (const float*)d_in[13]; const float* bg1 = (const float*)d_in[14];
    const float* wg2 = (const float*)d_in[15]; const float* bg2 = (const float*)d_in[16];
    const float* wf1 = (const float*)d_in[17]; const float* bf1 = (const float*)d_in[18];
    const float* wf2 = (const float*)d_in[19]; const float* bf2 = (const float*)d_in[20];
    const float* wf3 = (const float*)d_in[21]; const float* bf3 = (const float*)d_in[22];
    const float* wlin = (const float*)d_in[23]; const float* blin = (const float*)d_in[24];
    const float* wgd1 = (const float*)d_in[25]; const float* bgd1 = (const float*)d_in[26];
    const float* wgd2 = (const float*)d_in[27]; const float* bgd2 = (const float*)d_in[28];
    const float* wau1 = (const float*)d_in[29]; const float* bau1 = (const float*)d_in[30];
    const float* wau2 = (const float*)d_in[31]; const float* bau2 = (const float*)d_in[32];
    const float* wav1 = (const float*)d_in[33]; const float* bav1 = (const float*)d_in[34];
    const float* wav2 = (const float*)d_in[35]; const float* bav2 = (const float*)d_in[36];
    float* out = (float*)d_out;

    float* ws = (float*)d_ws;
    float* t0    = ws;
    float* t1    = t0 + 524288;
    float* t2    = t1 + 262144;
    float* splat = t2 + 131072;
    float* l0o   = splat + 65536;
    float* local = l0o + 65536;
    float* x1    = local + 65536;
    float* x2    = x1 + 32768;
    float* avec  = x2 + 16384;
    float* glob  = avec + 1792;
    float* gridb = glob + 256;

    // splat stack
    conv3x3_s2_relu<<<2048, 256, 0, stream>>>(low, w0, b0, t0, 4, 3, 256, 256, 8, 128, 128);
    conv3x3_s2_relu<<<1024, 256, 0, stream>>>(t0, w1, b1, t1, 4, 8, 128, 128, 16, 64, 64);
    conv3x3_s2_relu<<<512, 256, 0, stream>>>(t1, w2, b2, t2, 4, 16, 64, 64, 32, 32, 32);
    conv3x3_s2_relu<<<256, 256, 0, stream>>>(t2, w3, b3, splat, 4, 32, 32, 32, 64, 16, 16);
    // local branch
    conv3x3_s1_64<<<256, 256, 0, stream>>>(splat, wl0, bl0, l0o, 1);
    conv3x3_s1_64<<<256, 256, 0, stream>>>(l0o, wl1, nullptr, local, 0);
    // global branch
    conv3x3_s2_relu<<<128, 256, 0, stream>>>(splat, wg1, bg1, x1, 4, 64, 16, 16, 128, 8, 8);
    conv3x3_s2_relu<<<64, 256, 0, stream>>>(x1, wg2, bg2, x2, 4, 128, 8, 8, 256, 4, 4);
    means_kernel<<<7, 256, 0, stream>>>(splat, x1, x2, avec);
    fc_fused<<<4, 256, 0, stream>>>(avec, wf1, bf1, wf2, bf2, wf3, bf3, glob);
    // fuse + 1x1 linear -> bilateral grid
    fuse_grid<<<384, 256, 0, stream>>>(glob, local, wlin, blin, gridb);
    // fused full-res output
    hdr_out_kernel<<<16384, 256, 0, stream>>>(full, low, gridb,
        wgd1, bgd1, wgd2, bgd2, wau1, bau1, wau2, bau2, wav1, bav1, wav2, bav2, out);
}

// Round 2
// 393.792 us; speedup vs baseline: 1.7063x; 1.7063x over previous
//
#include <hip/hip_runtime.h>
#include <math.h>

// ---------------------------------------------------------------------------
// HDRNet pipeline, N=4, low 256x256, full 1024x1024.
// Workspace float layout (fp32):
//   t0 (4,8,128,128) 524288 | t1 (4,16,64,64) 262144 | t2 (4,32,32,32) 131072
//   splat (4,64,16,16) 65536 | l0o 65536 | local 65536
//   x1 (4,128,8,8) 32768 | x2 (4,256,4,4) 16384
//   avec 1792 | h1 1024 | h2 512 | glob 256
//   grid (4,8,16,16,12) 98304   <- channel-innermost for vectorized slice
// ---------------------------------------------------------------------------

__device__ __forceinline__ float tanh_fast(float x) {
    float e = __expf(2.0f * x);
    return 1.0f - 2.0f / (e + 1.0f);
}

// Generic 3x3 stride-2 pad-1 conv + bias + relu, thread-per-output.
// Used only for the first two convs (small Cin, huge grids).
__global__ __launch_bounds__(256) void conv3x3_s2_relu(
    const float* __restrict__ in, const float* __restrict__ w,
    const float* __restrict__ b, float* __restrict__ out,
    int N, int Cin, int Hin, int Win, int Cout, int Hout, int Wout)
{
    int idx = blockIdx.x * blockDim.x + threadIdx.x;
    int total = N * Cout * Hout * Wout;
    if (idx >= total) return;
    int wo = idx % Wout; int t = idx / Wout;
    int ho = t % Hout; t /= Hout;
    int co = t % Cout; int n = t / Cout;
    float acc = b[co];
    int hi0 = ho * 2 - 1, wi0 = wo * 2 - 1;
    const float* wp = w + (size_t)co * Cin * 9;
    for (int ci = 0; ci < Cin; ++ci) {
        const float* ip = in + ((size_t)(n * Cin + ci)) * Hin * Win;
        const float* wc = wp + ci * 9;
        #pragma unroll
        for (int kh = 0; kh < 3; ++kh) {
            int hi = hi0 + kh;
            if ((unsigned)hi >= (unsigned)Hin) continue;
            const float* row = ip + hi * Win;
            #pragma unroll
            for (int kw = 0; kw < 3; ++kw) {
                int wi = wi0 + kw;
                if ((unsigned)wi >= (unsigned)Win) continue;
                acc = fmaf(wc[kh * 3 + kw], row[wi], acc);
            }
        }
    }
    out[idx] = fmaxf(acc, 0.0f);
}

// 3x3 conv, pad 1, 4-way input-channel split: block = 256 threads =
// 4 parts x 64 outputs. Part p accumulates ci in [p*CIN/4,(p+1)*CIN/4),
// LDS-reduce, part 0 writes. 4x grid size + 4x shorter dep chains vs
// thread-per-output (fixes the 131us latency-bound wg2 dispatch).
template<int CIN, int STRIDE, bool RELU, bool HASB>
__global__ __launch_bounds__(256) void conv_split(
    const float* __restrict__ in, const float* __restrict__ w,
    const float* __restrict__ b, float* __restrict__ out,
    int Cout, int Hin, int Win, int Hout, int Wout)
{
    constexpr int CPT = CIN / 4;
    int part = threadIdx.x >> 6;
    int lane = threadIdx.x & 63;
    int o = (blockIdx.x << 6) | lane;
    int wo = o % Wout; int t = o / Wout;
    int ho = t % Hout; t /= Hout;
    int co = t % Cout; int n = t / Cout;
    int hi0 = ho * STRIDE - 1, wi0 = wo * STRIDE - 1;
    const float* wp = w + ((size_t)co * CIN + part * CPT) * 9;
    const float* ip = in + ((size_t)n * CIN + part * CPT) * Hin * Win;
    float acc = 0.0f;
    for (int ci = 0; ci < CPT; ++ci) {
        const float* ic = ip + (size_t)ci * Hin * Win;
        const float* wc = wp + ci * 9;
        #pragma unroll
        for (int kh = 0; kh < 3; ++kh) {
            int hi = hi0 + kh;
            if ((unsigned)hi >= (unsigned)Hin) continue;
            const float* row = ic + hi * Win;
            #pragma unroll
            for (int kw = 0; kw < 3; ++kw) {
                int wi = wi0 + kw;
                if ((unsigned)wi >= (unsigned)Win) continue;
                acc = fmaf(wc[kh * 3 + kw], row[wi], acc);
            }
        }
    }
    __shared__ float red[256];
    red[threadIdx.x] = acc;
    __syncthreads();
    if (part == 0) {
        float s = acc + red[64 + lane] + red[128 + lane] + red[192 + lane];
        if (HASB) s += b[co];
        if (RELU) s = fmaxf(s, 0.0f);
        out[o] = s;
    }
}

// Channel means -> avec[n][448]. One wave per (n,c).
__global__ __launch_bounds__(256) void means_kernel(
    const float* __restrict__ splat, const float* __restrict__ x1,
    const float* __restrict__ x2, float* __restrict__ avec)
{
    int wid = blockIdx.x * 4 + (threadIdx.x >> 6);   // 0..1791
    int lane = threadIdx.x & 63;
    int n = wid / 448; int c = wid % 448;
    float s = 0.0f; float scale;
    if (c < 64) {
        const float* p = splat + ((size_t)(n * 64 + c)) * 256;
        s = p[lane] + p[lane + 64] + p[lane + 128] + p[lane + 192];
        scale = 1.0f / 256.0f;
    } else if (c < 192) {
        const float* p = x1 + ((size_t)(n * 128 + (c - 64))) * 64;
        s = p[lane];
        scale = 1.0f / 64.0f;
    } else {
        const float* p = x2 + ((size_t)(n * 256 + (c - 192))) * 16;
        s = (lane < 16) ? p[lane] : 0.0f;
        scale = 1.0f / 16.0f;
    }
    #pragma unroll
    for (int off = 32; off; off >>= 1) s += __shfl_down(s, off, 64);
    if (lane == 0) avec[wid] = s * scale;
}

// FC layer + relu: one wave per output row, lane-split dot product.
template<int INDIM>
__global__ __launch_bounds__(256) void fc_relu(
    const float* __restrict__ in, const float* __restrict__ w,
    const float* __restrict__ b, float* __restrict__ out, int rows)
{
    int wid = blockIdx.x * 4 + (threadIdx.x >> 6);
    int lane = threadIdx.x & 63;
    int row = wid % rows; int n = wid / rows;
    const float* wp = w + (size_t)row * INDIM;
    const float* ip = in + (size_t)n * INDIM;
    float s = 0.0f;
    #pragma unroll
    for (int i = lane; i < INDIM; i += 64) s = fmaf(wp[i], ip[i], s);
    #pragma unroll
    for (int off = 32; off; off >>= 1) s += __shfl_down(s, off, 64);
    if (lane == 0) out[n * rows + row] = fmaxf(s + b[row], 0.0f);
}

// grid[n][z][gy][gx][ch] = blin[k] + sum_c wlin[k][c]*relu(glob[n][c]+local[n][c][p])
// where k = ch*8 + z (reference reshape (N,96,16,16)->(N,12,8,16,16)).
__global__ __launch_bounds__(256) void fuse_grid(
    const float* __restrict__ glob, const float* __restrict__ local,
    const float* __restrict__ wlin, const float* __restrict__ blin,
    float* __restrict__ grid)
{
    int idx = blockIdx.x * blockDim.x + threadIdx.x;   // 4*96*256
    int p = idx & 255; int k = (idx >> 8) % 96; int n = idx / (96 * 256);
    float acc = blin[k];
    const float* wp = wlin + k * 64;
    const float* gl = glob + n * 64;
    const float* lo = local + (size_t)n * 64 * 256 + p;
    for (int c = 0; c < 64; ++c)
        acc = fmaf(wp[c], fmaxf(gl[c] + lo[c * 256], 0.0f), acc);
    int ch = k >> 3; int z = k & 7;
    grid[(((size_t)(n * 8 + z)) * 256 + p) * 12 + ch] = acc;
}

// Fused full-res output, 4 pixels (one aligned float4 span) per thread.
__global__ __launch_bounds__(256) void hdr_out_v2(
    const float* __restrict__ full, const float* __restrict__ low,
    const float* __restrict__ grid,
    const float* __restrict__ wgd1, const float* __restrict__ bgd1,
    const float* __restrict__ wgd2, const float* __restrict__ bgd2,
    const float* __restrict__ wau1, const float* __restrict__ bau1,
    const float* __restrict__ wau2, const float* __restrict__ bau2,
    const float* __restrict__ wav1, const float* __restrict__ bav1,
    const float* __restrict__ wav2, const float* __restrict__ bav2,
    float* __restrict__ out)
{
    int tid = blockIdx.x * 256 + threadIdx.x;     // 1M threads
    int x0 = (tid & 255) << 2;
    int y = (tid >> 8) & 1023;
    int n = tid >> 18;
    const float* fp = full + ((size_t)n << 20);

    // 3 rows x 6 cols neighborhood, zero padded
    float v[3][6];
    #pragma unroll
    for (int r = 0; r < 3; ++r) {
        int yy = y + r - 1;
        bool okr = (unsigned)yy < 1024u;
        const float* row = fp + (size_t)yy * 1024;
        if (okr) {
            float4 m = *(const float4*)(row + x0);
            v[r][1] = m.x; v[r][2] = m.y; v[r][3] = m.z; v[r][4] = m.w;
            v[r][0] = (x0 > 0) ? row[x0 - 1] : 0.0f;
            v[r][5] = (x0 < 1020) ? row[x0 + 4] : 0.0f;
        } else {
            #pragma unroll
            for (int j = 0; j < 6; ++j) v[r][j] = 0.0f;
        }
    }

    // guide conv: 16ch 3x3 + relu + 1x1 + tanh; weights loaded once per 4 px
    float gacc[4];
    float bb = bgd2[0];
    #pragma unroll
    for (int px = 0; px < 4; ++px) gacc[px] = bb;
    #pragma unroll
    for (int k = 0; k < 16; ++k) {
        const float* wk = wgd1 + k * 9;
        float w0 = wk[0], w1 = wk[1], w2 = wk[2];
        float w3 = wk[3], w4 = wk[4], w5 = wk[5];
        float w6 = wk[6], w7 = wk[7], w8 = wk[8];
        float bk = bgd1[k], wo = wgd2[k];
        #pragma unroll
        for (int px = 0; px < 4; ++px) {
            float h = bk;
            h = fmaf(w0, v[0][px], h); h = fmaf(w1, v[0][px + 1], h); h = fmaf(w2, v[0][px + 2], h);
            h = fmaf(w3, v[1][px], h); h = fmaf(w4, v[1][px + 1], h); h = fmaf(w5, v[1][px + 2], h);
            h = fmaf(w6, v[2][px], h); h = fmaf(w7, v[2][px + 1], h); h = fmaf(w8, v[2][px + 2], h);
            gacc[px] = fmaf(wo, fmaxf(h, 0.0f), gacc[px]);
        }
    }

    const float* gbase = grid + (size_t)n * 24576;   // 8*256*12
    float Yo[4], Uo[4], Vo[4];

    #pragma unroll
    for (int px = 0; px < 4; ++px) {
        int x = x0 + px;
        float g = tanh_fast(gacc[px]);

        float gxc = (x * (32.0f / 1023.0f) - 1.0f) * 0.5f;
        float gyc = (y * (32.0f / 1023.0f) - 1.0f) * 0.5f;
        float gzc = 4.0f * g + 3.5f;
        float x0f = floorf(gxc), y0f = floorf(gyc), z0f = floorf(gzc);
        float fx = gxc - x0f, fy = gyc - y0f, fz = gzc - z0f;
        int ix = (int)x0f, iy = (int)y0f, iz = (int)z0f;

        float wx0 = (ix >= 0 && ix < 16) ? (1.0f - fx) : 0.0f;
        float wx1 = (ix + 1 >= 0 && ix + 1 < 16) ? fx : 0.0f;
        float wy0 = (iy >= 0 && iy < 16) ? (1.0f - fy) : 0.0f;
        float wy1 = (iy + 1 >= 0 && iy + 1 < 16) ? fy : 0.0f;
        float wz0 = (iz >= 0 && iz < 8) ? (1.0f - fz) : 0.0f;
        float wz1 = (iz + 1 >= 0 && iz + 1 < 8) ? fz : 0.0f;
        int xi0 = min(max(ix, 0), 15), xi1 = min(max(ix + 1, 0), 15);
        int yi0 = min(max(iy, 0), 15), yi1 = min(max(iy + 1, 0), 15);
        int zi0 = min(max(iz, 0), 7),  zi1 = min(max(iz + 1, 0), 7);

        float w00 = wy0 * wx0, w01 = wy0 * wx1, w10 = wy1 * wx0, w11 = wy1 * wx1;
        int o00 = yi0 * 16 + xi0, o01 = yi0 * 16 + xi1;
        int o10 = yi1 * 16 + xi0, o11 = yi1 * 16 + xi1;
        int z0b = zi0 * 256, z1b = zi1 * 256;

        float acc[12];
        #pragma unroll
        for (int i = 0; i < 12; ++i) acc[i] = 0.0f;

        #define CORNER(OFF, WK) { \
            const float4* q = (const float4*)(gbase + (size_t)(OFF) * 12); \
            float wk_ = (WK); \
            float4 A = q[0], B = q[1], C = q[2]; \
            acc[0] = fmaf(wk_, A.x, acc[0]); acc[1] = fmaf(wk_, A.y, acc[1]); \
            acc[2] = fmaf(wk_, A.z, acc[2]); acc[3] = fmaf(wk_, A.w, acc[3]); \
            acc[4] = fmaf(wk_, B.x, acc[4]); acc[5] = fmaf(wk_, B.y, acc[5]); \
            acc[6] = fmaf(wk_, B.z, acc[6]); acc[7] = fmaf(wk_, B.w, acc[7]); \
            acc[8] = fmaf(wk_, C.x, acc[8]); acc[9] = fmaf(wk_, C.y, acc[9]); \
            acc[10] = fmaf(wk_, C.z, acc[10]); acc[11] = fmaf(wk_, C.w, acc[11]); }

        CORNER(z0b + o00, wz0 * w00)
        CORNER(z0b + o01, wz0 * w01)
        CORNER(z0b + o10, wz0 * w10)
        CORNER(z0b + o11, wz0 * w11)
        CORNER(z1b + o00, wz1 * w00)
        CORNER(z1b + o01, wz1 * w01)
        CORNER(z1b + o10, wz1 * w10)
        CORNER(z1b + o11, wz1 * w11)
        #undef CORNER

        float p = v[1][px + 1];
        float Yv = fmaf(p, acc[3],  acc[0] + acc[1] + acc[2]);
        float U0 = fmaf(p, acc[7],  acc[4] + acc[5] + acc[6]);
        float V0 = fmaf(p, acc[11], acc[8] + acc[9] + acc[10]);

        float uacc = bau2[0];
        #pragma unroll
        for (int k = 0; k < 16; ++k)
            uacc = fmaf(wau2[k], fmaxf(fmaf(wau1[k], U0, bau1[k]), 0.0f), uacc);
        float vacc = bav2[0];
        #pragma unroll
        for (int k = 0; k < 16; ++k)
            vacc = fmaf(wav2[k], fmaxf(fmaf(wav1[k], V0, bav1[k]), 0.0f), vacc);

        // bilinear 256->1024 fake chroma
        float sx = (x + 0.5f) * 0.25f - 0.5f;
        float sy = (y + 0.5f) * 0.25f - 0.5f;
        float sxf = floorf(sx), syf = floorf(sy);
        float fxl = sx - sxf, fyl = sy - syf;
        int jx0 = max((int)sxf, 0), jx1 = min((int)sxf + 1, 255);
        int jy0 = max((int)syf, 0), jy1 = min((int)syf + 1, 255);
        const float* lr1 = low + ((size_t)(n * 3 + 1)) * 65536;
        const float* lr2 = low + ((size_t)(n * 3 + 2)) * 65536;
        float f1 = (1.0f - fyl) * ((1.0f - fxl) * lr1[jy0 * 256 + jx0] + fxl * lr1[jy0 * 256 + jx1])
                 + fyl * ((1.0f - fxl) * lr1[jy1 * 256 + jx0] + fxl * lr1[jy1 * 256 + jx1]);
        float f2 = (1.0f - fyl) * ((1.0f - fxl) * lr2[jy0 * 256 + jx0] + fxl * lr2[jy0 * 256 + jx1])
                 + fyl * ((1.0f - fxl) * lr2[jy1 * 256 + jx0] + fxl * lr2[jy1 * 256 + jx1]);

        Yo[px] = Yv;
        Uo[px] = tanh_fast(uacc) + f1;
        Vo[px] = tanh_fast(vacc) + f2;
    }

    size_t base = ((size_t)n * 3) * 1048576 + (size_t)y * 1024 + x0;
    *(float4*)(out + base)            = make_float4(Yo[0], Yo[1], Yo[2], Yo[3]);
    *(float4*)(out + base + 1048576)  = make_float4(Uo[0], Uo[1], Uo[2], Uo[3]);
    *(float4*)(out + base + 2097152)  = make_float4(Vo[0], Vo[1], Vo[2], Vo[3]);
}

extern "C" void kernel_launch(void* const* d_in, const int* in_sizes, int n_in,
                              void* d_out, int out_size, void* d_ws, size_t ws_size,
                              hipStream_t stream)
{
    const float* low  = (const float*)d_in[0];
    const float* full = (const float*)d_in[1];
    const float* w0 = (const float*)d_in[2];  const float* b0 = (const float*)d_in[3];
    const float* w1 = (const float*)d_in[4];  const float* b1 = (const float*)d_in[5];
    const float* w2 = (const float*)d_in[6];  const float* b2 = (const float*)d_in[7];
    const float* w3 = (const float*)d_in[8];  const float* b3 = (const float*)d_in[9];
    const float* wl0 = (const float*)d_in[10]; const float* bl0 = (const float*)d_in[11];
    const float* wl1 = (const float*)d_in[12];
    const float* wg1 = (const float*)d_in[13]; const float* bg1 = (const float*)d_in[14];
    const float* wg2 = (const float*)d_in[15]; const float* bg2 = (const float*)d_in[16];
    const float* wf1 = (const float*)d_in[17]; const float* bf1 = (const float*)d_in[18];
    const float* wf2 = (const float*)d_in[19]; const float* bf2 = (const float*)d_in[20];
    const float* wf3 = (const float*)d_in[21]; const float* bf3 = (const float*)d_in[22];
    const float* wlin = (const float*)d_in[23]; const float* blin = (const float*)d_in[24];
    const float* wgd1 = (const float*)d_in[25]; const float* bgd1 = (const float*)d_in[26];
    const float* wgd2 = (const float*)d_in[27]; const float* bgd2 = (const float*)d_in[28];
    const float* wau1 = (const float*)d_in[29]; const float* bau1 = (const float*)d_in[30];
    const float* wau2 = (const float*)d_in[31]; const float* bau2 = (const float*)d_in[32];
    const float* wav1 = (const float*)d_in[33]; const float* bav1 = (const float*)d_in[34];
    const float* wav2 = (const float*)d_in[35]; const float* bav2 = (const float*)d_in[36];
    float* out = (float*)d_out;

    float* ws = (float*)d_ws;
    float* t0    = ws;
    float* t1    = t0 + 524288;
    float* t2    = t1 + 262144;
    float* splat = t2 + 131072;
    float* l0o   = splat + 65536;
    float* local = l0o + 65536;
    float* x1    = local + 65536;
    float* x2    = x1 + 32768;
    float* avec  = x2 + 16384;
    float* h1    = avec + 1792;
    float* h2    = h1 + 1024;
    float* glob  = h2 + 512;
    float* gridb = glob + 256;

    // splat stack
    conv3x3_s2_relu<<<2048, 256, 0, stream>>>(low, w0, b0, t0, 4, 3, 256, 256, 8, 128, 128);
    conv3x3_s2_relu<<<1024, 256, 0, stream>>>(t0, w1, b1, t1, 4, 8, 128, 128, 16, 64, 64);
    conv_split<16, 2, true, true><<<2048, 256, 0, stream>>>(t1, w2, b2, t2, 32, 64, 64, 32, 32);
    conv_split<32, 2, true, true><<<1024, 256, 0, stream>>>(t2, w3, b3, splat, 64, 32, 32, 16, 16);
    // local branch
    conv_split<64, 1, true, true><<<1024, 256, 0, stream>>>(splat, wl0, bl0, l0o, 64, 16, 16, 16, 16);
    conv_split<64, 1, false, false><<<1024, 256, 0, stream>>>(l0o, wl1, nullptr, local, 64, 16, 16, 16, 16);
    // global branch
    conv_split<64, 2, true, true><<<512, 256, 0, stream>>>(splat, wg1, bg1, x1, 128, 16, 16, 8, 8);
    conv_split<128, 2, true, true><<<256, 256, 0, stream>>>(x1, wg2, bg2, x2, 256, 8, 8, 4, 4);
    means_kernel<<<448, 256, 0, stream>>>(splat, x1, x2, avec);
    fc_relu<448><<<256, 256, 0, stream>>>(avec, wf1, bf1, h1, 256);
    fc_relu<256><<<128, 256, 0, stream>>>(h1, wf2, bf2, h2, 128);
    fc_relu<128><<<64, 256, 0, stream>>>(h2, wf3, bf3, glob, 64);
    fuse_grid<<<384, 256, 0, stream>>>(glob, local, wlin, blin, gridb);
    // fused full-res output
    hdr_out_v2<<<4096, 256, 0, stream>>>(full, low, gridb,
        wgd1, bgd1, wgd2, bgd2, wau1, bau1, wau2, bau2, wav1, bav1, wav2, bav2, out);
}